// Round 21
// baseline (491.317 us; speedup 1.0000x reference)
//
#include <hip/hip_runtime.h>

namespace {

constexpr int Bn = 8192;
constexpr int Tn = 365;
constexpr int Hn = 34;
constexpr int GB = 16;      // batches per block -> grid 512, 2 blocks/CU
constexpr int KP = 72;      // a_lds row stride in halves (144 B; 2-way banks)

constexpr float L2E = 1.44269504088896340736f;

typedef __attribute__((ext_vector_type(8))) _Float16 f16x8;  // 8 fp16 = 4 VGPR
typedef __attribute__((ext_vector_type(4))) float f32x4;     // 16x16 MFMA acc

// cross-wave LDS barrier WITHOUT a vmcnt drain: LDS writes drained (lgkmcnt),
// then raw s_barrier. Global stores/loads stay in flight across steps.
__device__ __forceinline__ void block_sync_lds() {
    __builtin_amdgcn_sched_barrier(0);
    asm volatile("s_waitcnt lgkmcnt(0)" ::: "memory");
    __builtin_amdgcn_s_barrier();
    __builtin_amdgcn_sched_barrier(0);
}

// ---- R21: ZERO-TRANS nonlinearity ---------------------------------------
// Session fit (R10/R13: 1-wave walls 3020-3175 cyc ~ 85 trans x 32; R16-R20:
// walls ~2366 ~ 42.5 trans x 32 + measured VALU): wave64 transcendentals cost
// ~32 issue cycles each; trans+VALU = 93% of the step wall -> issue-bound.
// Replace exp2/rcp with full-rate VALU polys:
//   nlcore(acc) = 1/(1+2^-|acc|) - 0.5, via:
//     2^r (r in [-.5,.5]) deg-4 poly + exponent-bit ldexp   (~1e-7)
//     1/(1+e) deg-3 Chebyshev init + 1 Newton step          (<=6e-6)
// sig(v)=1/(1+2^acc) and tanh both derive by sign symmetry. ~18 VALU vs
// 2 trans+4 VALU: per-cell nonlin issue 330 -> ~200 cyc.
__device__ __forceinline__ float nlcore(float acc) {
    const float m = fmaxf(-fabsf(acc), -24.f);     // -abs folds as modifier
    const float i = rintf(m);
    const float r = m - i;                          // [-0.5, 0.5]
    const float q = fmaf(r, fmaf(r, fmaf(r, fmaf(r, 0.0096732f,
                         0.0554818f), 0.2402265f), 0.6931472f), 1.0f);
    const float e = q * __int_as_float(((int)i + 127) << 23);  // 2^m, no denorm (m>=-24)
    const float y0 = fmaf(e, fmaf(e, fmaf(e, -0.228584f, 0.675920f),
                          -0.946908f), 0.998525f); // ~1/(1+e), err ~1.7e-3
    const float y  = y0 * fmaf(-(1.f + e), y0, 2.f);           // Newton -> ~6e-6
    return y - 0.5f;                                // in [~0, 0.5)
}
__device__ __forceinline__ float sig2(float acc) {  // 1/(1+2^acc)
    const float x = nlcore(acc);
    return (acc <= 0.f) ? (0.5f + x) : (0.5f - x);
}
// sc * tanh(v) where acc = 2*L2E*v  (sc compile-time: 1 for h, 2*L2E for c-domain g)
__device__ __forceinline__ float tanh2(float acc, float sc) {
    const float x = nlcore(acc);
    const float t = (2.f * sc) * x;
    return (acc > 0.f) ? t : -t;
}
// --------------------------------------------------------------------------

// FP16 K-layout (42 used of 64; pads stay zero). fp16 products exact in f32
// MFMA accumulate. Weight rows PRE-SCALED by s(gate): -log2e (i,f,o) /
// +2*log2e (g) so acc feeds sig2/tanh2 directly.
//   k 0-33 : h[j]   <-> fp16(s*w_hh[r][j])
//   k 34-36: x_h[i] <-> fp16(s*Wc[r][i])
//   k 37-39: x_l[i] <-> fp16(s*Wc[r][i])     (x_l = x - fp16(x))
//   k 40   : 1.0    <-> bias_h ;  k 41 : 1.0 <-> bias_l
// SWAPPED-OPERAND MFMA (R16): lane (kg,b) holds gates i,f,g,o of cell
// jl = 4*tau+kg, batch b -> cell update LANE-LOCAL. One s_barrier/step.
// Cell state kept in C-domain: C = 2*L2E*c (tanh2 consumes C with no mul).
// R20's x pipeline retained (load -> hold-reg -> stage, 2-step distance).

__global__ __launch_bounds__(256) void lstm_kernel(
    const float* __restrict__ x,      // [B,T,3]
    const float* __restrict__ fc0_w,  // [34,3]
    const float* __restrict__ fc0_b,  // [34]
    const float* __restrict__ w_ih,   // [136,34]
    const float* __restrict__ w_hh,   // [136,34]
    const float* __restrict__ b_ih,   // [136]
    const float* __restrict__ b_hh,   // [136]
    float* __restrict__ out)          // [B,T,34]
{
    __shared__ __align__(16) _Float16 a_lds[2][GB][KP]; // h/x operand, double-buffered

    const int tid  = threadIdx.x;
    const int lane = tid & 63;
    const int wv   = tid >> 6;      // wave id
    const int b    = lane & 15;     // batch (D col); tile-row rho when building W
    const int kg   = lane >> 4;     // k-group; D-row group

    // cell partition across waves: {9,9,8,8}
    const int nc   = (wv < 2) ? 9 : 8;
    const int base = (wv < 2) ? 9 * wv : 18 + 8 * (wv - 2);

    // ---- one-time: weight A-fragments (3 N-tiles x 2 K-chunks), prescaled fp16 ----
    f16x8 Wt[3][2];
    #pragma unroll
    for (int tau = 0; tau < 3; ++tau) {
        const int rhat = 16 * tau + b;
        const int jl = rhat >> 2, g = rhat & 3;
        const int r = (jl < nc) ? g * Hn + (base + jl) : -1;
        const float s = (g == 2) ? (2.f * L2E) : (-L2E);
        float swc[3] = {0.f, 0.f, 0.f};
        float bia = 0.f;
        if (r >= 0) {
            float ab = 0.f;
            for (int m = 0; m < Hn; ++m) {
                const float wi = w_ih[r * Hn + m];
                swc[0] += wi * fc0_w[m * 3 + 0];
                swc[1] += wi * fc0_w[m * 3 + 1];
                swc[2] += wi * fc0_w[m * 3 + 2];
                ab     += wi * fc0_b[m];
            }
            swc[0] *= s; swc[1] *= s; swc[2] *= s;
            bia = s * (ab + b_ih[r] + b_hh[r]);
        }
        #pragma unroll
        for (int ks = 0; ks < 2; ++ks) {
            f16x8 f;
            #pragma unroll
            for (int e = 0; e < 8; ++e) {
                const int k = ks * 32 + kg * 8 + e;
                float val = 0.f;
                if (r >= 0) {
                    if (k < 34)       val = s * w_hh[r * Hn + k];
                    else if (k < 37)  val = swc[k - 34];
                    else if (k < 40)  val = swc[k - 37];
                    else if (k == 40) val = bia;                          // bias_h
                    else if (k == 41) val = bia - (float)(_Float16)bia;   // bias_l
                }
                f[e] = (_Float16)val;
            }
            Wt[tau][ks] = f;
        }
    }

    // lane-local cells: jl = 4*tau + kg (tau=0,1 always valid; tau=2 iff 8+kg < nc)
    const bool has2 = (8 + kg < nc);
    float C0 = 0.f, C1 = 0.f, C2 = 0.f;   // cell state, C-domain (2*L2E*c)
    float h0 = 0.f, h1 = 0.f, h2 = 0.f;

    // x staging: wave w stages batches 4w..4w+3 (12 lanes x 1 feature)
    const bool xact = (lane < 12);
    const int bx = 4 * wv + lane / 3;
    const int ix = lane - 3 * (lane / 3);

    // ---- zero both A buffers; barrier; bias-1.0 slots + x(0); barrier ----
    for (int i = tid; i < 2 * GB * KP; i += 256) ((_Float16*)a_lds)[i] = (_Float16)0.f;
    block_sync_lds();

    const long long bg = (long long)blockIdx.x * GB;
    const float* xblk = x + bg * (long long)(Tn * 3);
    float* oblk = out + bg * (long long)(Tn * Hn);
    const long long TH = (long long)Tn * Hn;

    if (tid < 32) {   // constant-1.0 slots (bias path), both buffers
        a_lds[tid >> 4][tid & 15][40] = (_Float16)1.f;
        a_lds[tid >> 4][tid & 15][41] = (_Float16)1.f;
    }
    if (xact) {
        const float xr = xblk[bx * (Tn * 3) + ix];
        const _Float16 xh = (_Float16)xr;
        a_lds[0][bx][34 + ix] = xh;
        a_lds[0][bx][37 + ix] = (_Float16)(xr - (float)xh);
    }
    block_sync_lds();

    // prime the x pipeline: xr_hold = x(1)
    float xr_hold = 0.f;
    if (xact && 1 < Tn)
        xr_hold = xblk[bx * (Tn * 3) + 3 + ix];

    // pointer-hoisted output cursor (stores h(t-1) at top of step t)
    float* pr = oblk + (long long)b * TH + base;

    for (int t = 0; t < Tn; ++t) {
        const int cur = t & 1, nxt = cur ^ 1;

        // ---- (1) data B-fragments first ----
        f16x8 av[2];
        #pragma unroll
        for (int ks = 0; ks < 2; ++ks)
            av[ks] = *(const f16x8*)(&a_lds[cur][b][ks * 32 + kg * 8]);

        // ---- (2) stage x(t+1) from xr_hold (load >= 1 step old) ----
        if (xact) {
            const _Float16 xh = (_Float16)xr_hold;
            a_lds[nxt][bx][34 + ix] = xh;
            a_lds[nxt][bx][37 + ix] = (_Float16)(xr_hold - (float)xh);
        }

        // ---- (3) h(t-1) stores (fire-and-forget) ----
        if (t) {
            pr[kg]     = h0;
            pr[4 + kg] = h1;
            if (has2) pr[8 + kg] = h2;
            pr += Hn;
        }

        // ---- (4) issue x(t+2) load ----
        float xr_next = 0.f;
        if (xact && t + 2 < Tn)
            xr_next = xblk[bx * (Tn * 3) + (t + 2) * 3 + ix];

        // ---- MFMA (swapped): acc[tau] regs = gates i,f,g,o of cell 4*tau+kg ----
        f32x4 acc[3];
        #pragma unroll
        for (int tau = 0; tau < 3; ++tau) {
            acc[tau] = f32x4{0.f, 0.f, 0.f, 0.f};
            #pragma unroll
            for (int ks = 0; ks < 2; ++ks)
                acc[tau] = __builtin_amdgcn_mfma_f32_16x16x32_f16(Wt[tau][ks], av[ks], acc[tau], 0, 0, 0);
        }

        // ---- lane-local nonlinearity (all-VALU polys) + cell update ----
        {
            const float gi = sig2(acc[0][0]);
            const float gf = sig2(acc[0][1]);
            const float gG = tanh2(acc[0][2], 2.f * L2E);   // g-gate, C-domain scaled
            const float go = sig2(acc[0][3]);
            C0 = gf * C0 + gi * gG;
            h0 = go * tanh2(C0, 1.f);
            a_lds[nxt][b][base + kg] = (_Float16)h0;
        }
        {
            const float gi = sig2(acc[1][0]);
            const float gf = sig2(acc[1][1]);
            const float gG = tanh2(acc[1][2], 2.f * L2E);
            const float go = sig2(acc[1][3]);
            C1 = gf * C1 + gi * gG;
            h1 = go * tanh2(C1, 1.f);
            a_lds[nxt][b][base + 4 + kg] = (_Float16)h1;
        }
        if (has2) {
            const float gi = sig2(acc[2][0]);
            const float gf = sig2(acc[2][1]);
            const float gG = tanh2(acc[2][2], 2.f * L2E);
            const float go = sig2(acc[2][3]);
            C2 = gf * C2 + gi * gG;
            h2 = go * tanh2(C2, 1.f);
            a_lds[nxt][b][base + 8 + kg] = (_Float16)h2;
        }

        xr_hold = xr_next;   // advance the x pipeline

        block_sync_lds();    // the ONE sync/step: h(t) visible to all waves
    }

    // final store: h(Tn-1)
    {
        pr[kg]     = h0;
        pr[4 + kg] = h1;
        if (has2) pr[8 + kg] = h2;
    }
}

} // namespace

extern "C" void kernel_launch(void* const* d_in, const int* in_sizes, int n_in,
                              void* d_out, int out_size, void* d_ws, size_t ws_size,
                              hipStream_t stream) {
    const float* x     = (const float*)d_in[0];
    const float* fc0_w = (const float*)d_in[1];
    const float* fc0_b = (const float*)d_in[2];
    const float* w_ih  = (const float*)d_in[3];
    const float* w_hh  = (const float*)d_in[4];
    const float* b_ih  = (const float*)d_in[5];
    const float* b_hh  = (const float*)d_in[6];
    float* out = (float*)d_out;

    lstm_kernel<<<Bn / GB, 256, 0, stream>>>(x, fc0_w, fc0_b, w_ih, w_hh, b_ih, b_hh, out);
}

// Round 22
// 374.133 us; speedup vs baseline: 1.3132x; 1.3132x over previous
//
#include <hip/hip_runtime.h>

namespace {

constexpr int Bn = 8192;
constexpr int Tn = 365;
constexpr int Hn = 34;
constexpr int GB = 32;      // TWO 16-batch groups per block -> grid 256, 1 block/CU
constexpr int NT = 512;     // 8 waves
constexpr int KP = 72;      // a_lds row stride in halves (144 B; 2-way banks)

constexpr float L2E = 1.44269504088896340736f;

typedef __attribute__((ext_vector_type(8))) _Float16 f16x8;  // 8 fp16 = 4 VGPR
typedef __attribute__((ext_vector_type(4))) float f32x4;     // 16x16 MFMA acc

__device__ __forceinline__ float fexp2(float v) { return __builtin_amdgcn_exp2f(v); }
__device__ __forceinline__ float frcp(float v)  { return __builtin_amdgcn_rcpf(v); }

// cross-wave LDS barrier WITHOUT a vmcnt drain: LDS writes drained (lgkmcnt),
// then raw s_barrier. Global stores/loads stay in flight across steps.
__device__ __forceinline__ void block_sync_lds() {
    __builtin_amdgcn_sched_barrier(0);
    asm volatile("s_waitcnt lgkmcnt(0)" ::: "memory");
    __builtin_amdgcn_s_barrier();
    __builtin_amdgcn_sched_barrier(0);
}

// FP16 K-layout (42 used of 64; pads stay zero). fp16 products exact in f32
// MFMA accumulate. Weight rows PRE-SCALED by s(gate): -log2e (i,f,o) /
// +2*log2e (g):  sigmoid = rcp(1+exp2(acc)), tanh = fma(-2,rcp(1+exp2(acc)),1).
//   k 0-33 : h[j] ; k 34-36: x_h ; k 37-39: x_l ; k 40: bias_h*1 ; k 41: bias_l*1
//
// R22: TWO BATCH-GROUPS PER BARRIER INTERVAL. R15-R20 invariant: wall/step =
// issue (1240 cyc/SIMD) + ~1075 exposed chain/skew, insensitive to barrier
// flavor, occupancy, store placement (R19/R20/R21 refuted TA / vmcnt-FIFO /
// trans-cost theories). Fix attempt: each wave owns ONE cell-tile (1 cell/
// lane; wave 7 gets half-tile 8 too) and runs TWO independent 16-batch groups
// per step — group B's instructions fill group A's dependent-chain stalls
// (in-wave ILP, compiler-scheduled), and one barrier serves 32 batches.
// Per-SIMD issue unchanged; exposed latency should shrink.

__global__ __launch_bounds__(NT) void lstm_kernel(
    const float* __restrict__ x,      // [B,T,3]
    const float* __restrict__ fc0_w,  // [34,3]
    const float* __restrict__ fc0_b,  // [34]
    const float* __restrict__ w_ih,   // [136,34]
    const float* __restrict__ w_hh,   // [136,34]
    const float* __restrict__ b_ih,   // [136]
    const float* __restrict__ b_hh,   // [136]
    float* __restrict__ out)          // [B,T,34]
{
    __shared__ __align__(16) _Float16 a_lds[2][GB][KP]; // [buf][group*16+b][k]

    const int tid  = threadIdx.x;
    const int lane = tid & 63;
    const int wv   = tid >> 6;      // wave id 0..7 = cell-tile id
    const int b    = lane & 15;     // batch within group (D col); W tile-row when building
    const int kg   = lane >> 4;     // k-group; D-row group

    // ---- one-time: weight A-fragments, prescaled fp16 ----
    // tile wv: global rhat = 16*wv + rho (rho = b) -> cell 4*wv+(b>>2), gate b&3
    // wave 7 extra: tile 8, rhat = 128 + rho, valid rho<8 (cells 32,33)
    f16x8 Wt[2], Wt2[2];
    #pragma unroll
    for (int ti = 0; ti < 2; ++ti) {
        const bool second = (ti == 1);
        if (second && wv != 7) { Wt2[0] = f16x8{}; Wt2[1] = f16x8{}; continue; }
        const int cell = second ? (32 + (b >> 2)) : (4 * wv + (b >> 2));
        const int g    = b & 3;
        const bool valid = second ? (b < 8) : true;
        const int r = g * Hn + (valid ? cell : 0);
        const float s = (g == 2) ? (2.f * L2E) : (-L2E);
        float swc[3] = {0.f, 0.f, 0.f};
        float bia = 0.f;
        if (valid) {
            float ab = 0.f;
            for (int m = 0; m < Hn; ++m) {
                const float wi = w_ih[r * Hn + m];
                swc[0] += wi * fc0_w[m * 3 + 0];
                swc[1] += wi * fc0_w[m * 3 + 1];
                swc[2] += wi * fc0_w[m * 3 + 2];
                ab     += wi * fc0_b[m];
            }
            swc[0] *= s; swc[1] *= s; swc[2] *= s;
            bia = s * (ab + b_ih[r] + b_hh[r]);
        }
        #pragma unroll
        for (int ks = 0; ks < 2; ++ks) {
            f16x8 f;
            #pragma unroll
            for (int e = 0; e < 8; ++e) {
                const int k = ks * 32 + kg * 8 + e;
                float val = 0.f;
                if (valid) {
                    if (k < 34)       val = s * w_hh[r * Hn + k];
                    else if (k < 37)  val = swc[k - 34];
                    else if (k < 40)  val = swc[k - 37];
                    else if (k == 40) val = bia;                          // bias_h
                    else if (k == 41) val = bia - (float)(_Float16)bia;   // bias_l
                }
                f[e] = (_Float16)val;
            }
            if (second) Wt2[ks] = f; else Wt[ks] = f;
        }
    }

    // lane-local cells: j0 = 4*wv + kg (tile wv); wave 7 extra j1 = 32+kg (kg<2)
    const int j0 = 4 * wv + kg;
    const bool hasx = (wv == 7) && (kg < 2);
    const int j1 = 32 + kg;

    float cA0 = 0.f, cB0 = 0.f, hA0 = 0.f, hB0 = 0.f;
    float cA1 = 0.f, cB1 = 0.f, hA1 = 0.f, hB1 = 0.f;

    // x staging: waves 0 (group A) and 1 (group B), lanes 0..47
    const bool xact = (wv < 2) && (lane < 48);
    const int bxg = wv * 16 + lane / 3;   // row 0..31 (group*16 + batch)
    const int ix  = lane - 3 * (lane / 3);

    // ---- zero both A buffers; barrier; bias slots + x(0); barrier ----
    for (int i = tid; i < 2 * GB * KP; i += NT) ((_Float16*)a_lds)[i] = (_Float16)0.f;
    block_sync_lds();

    const long long bg = (long long)blockIdx.x * GB;
    const float* xblk = x + bg * (long long)(Tn * 3);
    float* oblk = out + bg * (long long)(Tn * Hn);
    const long long TH = (long long)Tn * Hn;

    if (tid < 64) {   // constant-1.0 bias slots: [buf 0/1][rows 0..31]
        a_lds[tid >> 5][tid & 31][40] = (_Float16)1.f;
        a_lds[tid >> 5][tid & 31][41] = (_Float16)1.f;
    }
    if (tid < 96) {   // x(0) for all 32 batches
        const int b32 = tid / 3, i3 = tid - 3 * (tid / 3);
        const float xr = xblk[b32 * (Tn * 3) + i3];
        const _Float16 xh = (_Float16)xr;
        a_lds[0][b32][34 + i3] = xh;
        a_lds[0][b32][37 + i3] = (_Float16)(xr - (float)xh);
    }
    block_sync_lds();

    // prime the x pipeline: xr_hold = x(1)
    float xr_hold = 0.f;
    if (xact && 1 < Tn)
        xr_hold = xblk[bxg * (Tn * 3) + 3 + ix];

    // output cursors (store h(t-1) at top of step t)
    float* prA = oblk + (long long)b * TH + j0;
    float* prB = prA + 16 * TH;
    float* qrA = oblk + (long long)b * TH + j1;   // wave 7 extra cells
    float* qrB = qrA + 16 * TH;

    for (int t = 0; t < Tn; ++t) {
        const int cur = t & 1, nxt = cur ^ 1;

        // ---- (1) B-fragments for BOTH groups (4 ds_read_b128) ----
        f16x8 avA[2], avB[2];
        #pragma unroll
        for (int ks = 0; ks < 2; ++ks) {
            avA[ks] = *(const f16x8*)(&a_lds[cur][b][ks * 32 + kg * 8]);
            avB[ks] = *(const f16x8*)(&a_lds[cur][16 + b][ks * 32 + kg * 8]);
        }

        // ---- (2) stage x(t+1) from hold reg (load >= 1 step old) ----
        if (xact) {
            const _Float16 xh = (_Float16)xr_hold;
            a_lds[nxt][bxg][34 + ix] = xh;
            a_lds[nxt][bxg][37 + ix] = (_Float16)(xr_hold - (float)xh);
        }

        // ---- (3) h(t-1) stores (fire-and-forget) ----
        if (t) {
            prA[0] = hA0; prB[0] = hB0;
            if (hasx) { qrA[0] = hA1; qrB[0] = hB1; }
            prA += Hn; prB += Hn; qrA += Hn; qrB += Hn;
        }

        // ---- (4) issue x(t+2) load ----
        float xr_next = 0.f;
        if (xact && t + 2 < Tn)
            xr_next = xblk[bxg * (Tn * 3) + (t + 2) * 3 + ix];

        // ---- (5) MFMAs: acc regs = gates i,f,g,o of cell j0 (and j1 on wave 7) ----
        f32x4 aA = {0.f, 0.f, 0.f, 0.f}, aB = {0.f, 0.f, 0.f, 0.f};
        #pragma unroll
        for (int ks = 0; ks < 2; ++ks) {
            aA = __builtin_amdgcn_mfma_f32_16x16x32_f16(Wt[ks], avA[ks], aA, 0, 0, 0);
            aB = __builtin_amdgcn_mfma_f32_16x16x32_f16(Wt[ks], avB[ks], aB, 0, 0, 0);
        }
        f32x4 a2A = {0.f, 0.f, 0.f, 0.f}, a2B = {0.f, 0.f, 0.f, 0.f};
        if (wv == 7) {
            #pragma unroll
            for (int ks = 0; ks < 2; ++ks) {
                a2A = __builtin_amdgcn_mfma_f32_16x16x32_f16(Wt2[ks], avA[ks], a2A, 0, 0, 0);
                a2B = __builtin_amdgcn_mfma_f32_16x16x32_f16(Wt2[ks], avB[ks], a2B, 0, 0, 0);
            }
        }

        // ---- (6) lane-local nonlinearity + cell update; A/B chains interleave ----
        {
            const float gi = frcp(1.f + fexp2(aA[0]));
            const float gf = frcp(1.f + fexp2(aA[1]));
            const float gg = fmaf(-2.f, frcp(1.f + fexp2(aA[2])), 1.f);
            const float go = frcp(1.f + fexp2(aA[3]));
            cA0 = gf * cA0 + gi * gg;
            hA0 = go * fmaf(-2.f, frcp(1.f + fexp2(cA0 * (2.f * L2E))), 1.f);
            a_lds[nxt][b][j0] = (_Float16)hA0;
        }
        {
            const float gi = frcp(1.f + fexp2(aB[0]));
            const float gf = frcp(1.f + fexp2(aB[1]));
            const float gg = fmaf(-2.f, frcp(1.f + fexp2(aB[2])), 1.f);
            const float go = frcp(1.f + fexp2(aB[3]));
            cB0 = gf * cB0 + gi * gg;
            hB0 = go * fmaf(-2.f, frcp(1.f + fexp2(cB0 * (2.f * L2E))), 1.f);
            a_lds[nxt][16 + b][j0] = (_Float16)hB0;
        }
        if (hasx) {
            {
                const float gi = frcp(1.f + fexp2(a2A[0]));
                const float gf = frcp(1.f + fexp2(a2A[1]));
                const float gg = fmaf(-2.f, frcp(1.f + fexp2(a2A[2])), 1.f);
                const float go = frcp(1.f + fexp2(a2A[3]));
                cA1 = gf * cA1 + gi * gg;
                hA1 = go * fmaf(-2.f, frcp(1.f + fexp2(cA1 * (2.f * L2E))), 1.f);
                a_lds[nxt][b][j1] = (_Float16)hA1;
            }
            {
                const float gi = frcp(1.f + fexp2(a2B[0]));
                const float gf = frcp(1.f + fexp2(a2B[1]));
                const float gg = fmaf(-2.f, frcp(1.f + fexp2(a2B[2])), 1.f);
                const float go = frcp(1.f + fexp2(a2B[3]));
                cB1 = gf * cB1 + gi * gg;
                hB1 = go * fmaf(-2.f, frcp(1.f + fexp2(cB1 * (2.f * L2E))), 1.f);
                a_lds[nxt][16 + b][j1] = (_Float16)hB1;
            }
        }

        xr_hold = xr_next;   // advance the x pipeline

        block_sync_lds();    // ONE sync per step for BOTH groups
    }

    // final stores: h(Tn-1)
    {
        prA[0] = hA0; prB[0] = hB0;
        if (hasx) { qrA[0] = hA1; qrB[0] = hB1; }
    }
}

} // namespace

extern "C" void kernel_launch(void* const* d_in, const int* in_sizes, int n_in,
                              void* d_out, int out_size, void* d_ws, size_t ws_size,
                              hipStream_t stream) {
    const float* x     = (const float*)d_in[0];
    const float* fc0_w = (const float*)d_in[1];
    const float* fc0_b = (const float*)d_in[2];
    const float* w_ih  = (const float*)d_in[3];
    const float* w_hh  = (const float*)d_in[4];
    const float* b_ih  = (const float*)d_in[5];
    const float* b_hh  = (const float*)d_in[6];
    float* out = (float*)d_out;

    lstm_kernel<<<Bn / GB, NT, 0, stream>>>(x, fc0_w, fc0_b, w_ih, w_hh, b_ih, b_hh, out);
}

// Round 23
// 351.795 us; speedup vs baseline: 1.3966x; 1.0635x over previous
//
#include <hip/hip_runtime.h>

namespace {

constexpr int Bn = 8192;
constexpr int Tn = 365;
constexpr int Hn = 34;
constexpr int GB = 16;      // batches per block -> grid 512, 2 blocks/CU
constexpr int KP = 72;      // a_lds row stride in halves (144 B; 2-way banks)

constexpr float L2E = 1.44269504088896340736f;

typedef __attribute__((ext_vector_type(8))) _Float16 f16x8;  // 8 fp16 = 4 VGPR
typedef __attribute__((ext_vector_type(4))) float f32x4;     // 16x16 MFMA acc

__device__ __forceinline__ float fexp2(float v) { return __builtin_amdgcn_exp2f(v); }
__device__ __forceinline__ float frcp(float v)  { return __builtin_amdgcn_rcpf(v); }

// cross-wave LDS barrier WITHOUT a vmcnt drain: LDS writes drained (lgkmcnt),
// then raw s_barrier. Global stores/loads stay in flight across steps.
__device__ __forceinline__ void block_sync_lds() {
    __builtin_amdgcn_sched_barrier(0);
    asm volatile("s_waitcnt lgkmcnt(0)" ::: "memory");
    __builtin_amdgcn_s_barrier();
    __builtin_amdgcn_sched_barrier(0);
}

// FP16 K-layout (42 used of 64; pads stay zero). fp16 products exact in f32
// MFMA accumulate. Weight rows PRE-SCALED by s(gate): -log2e (i,f,o) /
// +2*log2e (g):  sigmoid = rcp(1+exp2(acc)), tanh = fma(-2,rcp(1+exp2(acc)),1).
//   k 0-33 : h[j] ; k 34-36: x_h ; k 37-39: x_l ; k 40: bias_h*1 ; k 41: bias_l*1
// SWAPPED-OPERAND MFMA (R16): lane (kg,b) holds gates i,f,g,o of cell
// jl = 4*tau+kg, batch b -> cell update LANE-LOCAL. One s_barrier/step.
// R20 x-pipeline: load -> hold-reg -> stage (2-step distance).
//
// R23: ANTI-PHASE CO-RESIDENT BLOCKS. Cross-round data (R10..R22): per-block
// step wall ~2300-2500 cyc across every occupancy/barrier/dtype variant while
// issue is ~700; R20 (2 blocks/CU) == R22 (1 fused block) in per-CU throughput
// -> blocks overlap fully but each block's chain never shrinks. Hypothesis:
// identical cadences phase-align the ds/trans bursts of the two co-resident
// blocks (dispatch: block b -> XCD b%8, CU (b/8)%32, so i and i+256 share a
// CU), stretching both chains by the collision. Fix: one-time ~1150-cyc
// s_sleep offset for the upper half of the grid -> persistent half-step
// phase shift; bursts land in the partner's stall windows.

__global__ __launch_bounds__(256) void lstm_kernel(
    const float* __restrict__ x,      // [B,T,3]
    const float* __restrict__ fc0_w,  // [34,3]
    const float* __restrict__ fc0_b,  // [34]
    const float* __restrict__ w_ih,   // [136,34]
    const float* __restrict__ w_hh,   // [136,34]
    const float* __restrict__ b_ih,   // [136]
    const float* __restrict__ b_hh,   // [136]
    float* __restrict__ out)          // [B,T,34]
{
    __shared__ __align__(16) _Float16 a_lds[2][GB][KP]; // h/x operand, double-buffered

    const int tid  = threadIdx.x;
    const int lane = tid & 63;
    const int wv   = tid >> 6;      // wave id
    const int b    = lane & 15;     // batch (D col); tile-row rho when building W
    const int kg   = lane >> 4;     // k-group; D-row group

    // cell partition across waves: {9,9,8,8}
    const int nc   = (wv < 2) ? 9 : 8;
    const int base = (wv < 2) ? 9 * wv : 18 + 8 * (wv - 2);

    // ---- one-time: weight A-fragments (3 N-tiles x 2 K-chunks), prescaled fp16 ----
    f16x8 Wt[3][2];
    #pragma unroll
    for (int tau = 0; tau < 3; ++tau) {
        const int rhat = 16 * tau + b;
        const int jl = rhat >> 2, g = rhat & 3;
        const int r = (jl < nc) ? g * Hn + (base + jl) : -1;
        const float s = (g == 2) ? (2.f * L2E) : (-L2E);
        float swc[3] = {0.f, 0.f, 0.f};
        float bia = 0.f;
        if (r >= 0) {
            float ab = 0.f;
            for (int m = 0; m < Hn; ++m) {
                const float wi = w_ih[r * Hn + m];
                swc[0] += wi * fc0_w[m * 3 + 0];
                swc[1] += wi * fc0_w[m * 3 + 1];
                swc[2] += wi * fc0_w[m * 3 + 2];
                ab     += wi * fc0_b[m];
            }
            swc[0] *= s; swc[1] *= s; swc[2] *= s;
            bia = s * (ab + b_ih[r] + b_hh[r]);
        }
        #pragma unroll
        for (int ks = 0; ks < 2; ++ks) {
            f16x8 f;
            #pragma unroll
            for (int e = 0; e < 8; ++e) {
                const int k = ks * 32 + kg * 8 + e;
                float val = 0.f;
                if (r >= 0) {
                    if (k < 34)       val = s * w_hh[r * Hn + k];
                    else if (k < 37)  val = swc[k - 34];
                    else if (k < 40)  val = swc[k - 37];
                    else if (k == 40) val = bia;                          // bias_h
                    else if (k == 41) val = bia - (float)(_Float16)bia;   // bias_l
                }
                f[e] = (_Float16)val;
            }
            Wt[tau][ks] = f;
        }
    }

    // lane-local cells: jl = 4*tau + kg (tau=0,1 always valid; tau=2 iff 8+kg < nc)
    const bool has2 = (8 + kg < nc);
    float c0 = 0.f, c1 = 0.f, c2 = 0.f;
    float h0 = 0.f, h1 = 0.f, h2 = 0.f;

    // x staging: wave w stages batches 4w..4w+3 (12 lanes x 1 feature)
    const bool xact = (lane < 12);
    const int bx = 4 * wv + lane / 3;
    const int ix = lane - 3 * (lane / 3);

    // ---- zero both A buffers; barrier; bias-1.0 slots + x(0); barrier ----
    for (int i = tid; i < 2 * GB * KP; i += 256) ((_Float16*)a_lds)[i] = (_Float16)0.f;
    block_sync_lds();

    const long long bg = (long long)blockIdx.x * GB;
    const float* xblk = x + bg * (long long)(Tn * 3);
    float* oblk = out + bg * (long long)(Tn * Hn);
    const long long TH = (long long)Tn * Hn;

    if (tid < 32) {   // constant-1.0 slots (bias path), both buffers
        a_lds[tid >> 4][tid & 15][40] = (_Float16)1.f;
        a_lds[tid >> 4][tid & 15][41] = (_Float16)1.f;
    }
    if (xact) {
        const float xr = xblk[bx * (Tn * 3) + ix];
        const _Float16 xh = (_Float16)xr;
        a_lds[0][bx][34 + ix] = xh;
        a_lds[0][bx][37 + ix] = (_Float16)(xr - (float)xh);
    }
    block_sync_lds();

    // ---- R23: phase-stagger the upper grid half (co-resident partner pairs
    // are (i, i+256) under XCD round-robin). ~18*64 ~ 1150 cyc = half a step.
    if (blockIdx.x >= 256)
        __builtin_amdgcn_s_sleep(18);

    // prime the x pipeline: xr_hold = x(1)
    float xr_hold = 0.f;
    if (xact && 1 < Tn)
        xr_hold = xblk[bx * (Tn * 3) + 3 + ix];

    // pointer-hoisted output cursor (stores h(t-1) at top of step t)
    float* pr = oblk + (long long)b * TH + base;

    for (int t = 0; t < Tn; ++t) {
        const int cur = t & 1, nxt = cur ^ 1;

        // ---- (1) data B-fragments first ----
        f16x8 av[2];
        #pragma unroll
        for (int ks = 0; ks < 2; ++ks)
            av[ks] = *(const f16x8*)(&a_lds[cur][b][ks * 32 + kg * 8]);

        // ---- (2) stage x(t+1) from xr_hold (load >= 1 step old: free wait) ----
        if (xact) {
            const _Float16 xh = (_Float16)xr_hold;
            a_lds[nxt][bx][34 + ix] = xh;
            a_lds[nxt][bx][37 + ix] = (_Float16)(xr_hold - (float)xh);
        }

        // ---- (3) h(t-1) stores (fire-and-forget) ----
        if (t) {
            pr[kg]     = h0;
            pr[4 + kg] = h1;
            if (has2) pr[8 + kg] = h2;
            pr += Hn;
        }

        // ---- (4) issue x(t+2) load ----
        float xr_next = 0.f;
        if (xact && t + 2 < Tn)
            xr_next = xblk[bx * (Tn * 3) + (t + 2) * 3 + ix];

        // ---- MFMA (swapped): acc[tau] regs = gates i,f,g,o of cell 4*tau+kg ----
        f32x4 acc[3];
        #pragma unroll
        for (int tau = 0; tau < 3; ++tau) {
            acc[tau] = f32x4{0.f, 0.f, 0.f, 0.f};
            #pragma unroll
            for (int ks = 0; ks < 2; ++ks)
                acc[tau] = __builtin_amdgcn_mfma_f32_16x16x32_f16(Wt[tau][ks], av[ks], acc[tau], 0, 0, 0);
        }

        // ---- lane-local nonlinearity + cell update (gate = reg index, static) ----
        {
            const float gi = frcp(1.f + fexp2(acc[0][0]));
            const float gf = frcp(1.f + fexp2(acc[0][1]));
            const float gg = fmaf(-2.f, frcp(1.f + fexp2(acc[0][2])), 1.f);
            const float go = frcp(1.f + fexp2(acc[0][3]));
            c0 = gf * c0 + gi * gg;
            h0 = go * fmaf(-2.f, frcp(1.f + fexp2(c0 * (2.f * L2E))), 1.f);
            a_lds[nxt][b][base + kg] = (_Float16)h0;
        }
        {
            const float gi = frcp(1.f + fexp2(acc[1][0]));
            const float gf = frcp(1.f + fexp2(acc[1][1]));
            const float gg = fmaf(-2.f, frcp(1.f + fexp2(acc[1][2])), 1.f);
            const float go = frcp(1.f + fexp2(acc[1][3]));
            c1 = gf * c1 + gi * gg;
            h1 = go * fmaf(-2.f, frcp(1.f + fexp2(c1 * (2.f * L2E))), 1.f);
            a_lds[nxt][b][base + 4 + kg] = (_Float16)h1;
        }
        if (has2) {
            const float gi = frcp(1.f + fexp2(acc[2][0]));
            const float gf = frcp(1.f + fexp2(acc[2][1]));
            const float gg = fmaf(-2.f, frcp(1.f + fexp2(acc[2][2])), 1.f);
            const float go = frcp(1.f + fexp2(acc[2][3]));
            c2 = gf * c2 + gi * gg;
            h2 = go * fmaf(-2.f, frcp(1.f + fexp2(c2 * (2.f * L2E))), 1.f);
            a_lds[nxt][b][base + 8 + kg] = (_Float16)h2;
        }

        xr_hold = xr_next;   // advance the x pipeline

        block_sync_lds();    // the ONE sync/step: h(t) visible to all waves
    }

    // final store: h(Tn-1)
    {
        pr[kg]     = h0;
        pr[4 + kg] = h1;
        if (has2) pr[8 + kg] = h2;
    }
}

} // namespace

extern "C" void kernel_launch(void* const* d_in, const int* in_sizes, int n_in,
                              void* d_out, int out_size, void* d_ws, size_t ws_size,
                              hipStream_t stream) {
    const float* x     = (const float*)d_in[0];
    const float* fc0_w = (const float*)d_in[1];
    const float* fc0_b = (const float*)d_in[2];
    const float* w_ih  = (const float*)d_in[3];
    const float* w_hh  = (const float*)d_in[4];
    const float* b_ih  = (const float*)d_in[5];
    const float* b_hh  = (const float*)d_in[6];
    float* out = (float*)d_out;

    lstm_kernel<<<Bn / GB, 256, 0, stream>>>(x, fc0_w, fc0_b, w_ih, w_hh, b_ih, b_hh, out);
}

// Round 24
// 347.538 us; speedup vs baseline: 1.4137x; 1.0122x over previous
//
#include <hip/hip_runtime.h>

namespace {

constexpr int Bn = 8192;
constexpr int Tn = 365;
constexpr int Hn = 34;
constexpr int GB = 16;      // batches per block -> grid 512, 2 blocks/CU
constexpr int KP = 72;      // a_lds row stride in halves (144 B; 2-way banks)

constexpr float L2E = 1.44269504088896340736f;

typedef __attribute__((ext_vector_type(8))) _Float16 f16x8;  // 8 fp16 = 4 VGPR
typedef __attribute__((ext_vector_type(4))) float f32x4;     // 16x16 MFMA acc

__device__ __forceinline__ float fexp2(float v) { return __builtin_amdgcn_exp2f(v); }
__device__ __forceinline__ float frcp(float v)  { return __builtin_amdgcn_rcpf(v); }

// cross-wave LDS barrier WITHOUT a vmcnt drain: LDS writes drained (lgkmcnt),
// then raw s_barrier. Global stores/loads stay in flight across steps.
__device__ __forceinline__ void block_sync_lds() {
    __builtin_amdgcn_sched_barrier(0);
    asm volatile("s_waitcnt lgkmcnt(0)" ::: "memory");
    __builtin_amdgcn_s_barrier();
}

// FP16 K-layout (42 used of 64; pads stay zero). fp16 products exact in f32
// MFMA accumulate. Weight rows PRE-SCALED by s(gate): -log2e (i,f,o) /
// +2*log2e (g), so with E = exp2(acc):
//   sigmoid = 1/(1+E),  tanh = (E-1)/(E+1).
//   k 0-33 : h[j] ; k 34-36: x_h ; k 37-39: x_l ; k 40: bias_h*1 ; k 41: bias_l*1
// SWAPPED-OPERAND MFMA (R16): lane (kg,b) holds gates i,f,g,o of cell
// jl = 4*tau+kg, batch b -> cell update LANE-LOCAL. One s_barrier/step.
// R20 x-pipeline: load -> hold-reg -> stage (2-step distance).
//
// R24: FUSED-RECIPROCAL GATING. The only lever that has ever moved the
// ~2315 cyc/step wall (R16, R18) is instruction reduction. Fuse:
//   i*g       = (Eg-1) / ((1+Ei)(1+Eg))      [one rcp instead of two]
//   o*tanh(c) = (Ec-1) / ((1+Eo)(1+Ec))      [one rcp instead of two]
// -> 5 exp2 + 3 rcp = 8 trans/cell vs 10. Clamp 2*L2E*c to +-80 before exp2
// (med3) so Ec never reaches inf (inf*rcp(inf) = NaN in the fused form).
// Gate pre-acts are bounded ~|W|*|h|+|Wc x|+|b| <= ~10 -> no clamp needed.

__global__ __launch_bounds__(256) void lstm_kernel(
    const float* __restrict__ x,      // [B,T,3]
    const float* __restrict__ fc0_w,  // [34,3]
    const float* __restrict__ fc0_b,  // [34]
    const float* __restrict__ w_ih,   // [136,34]
    const float* __restrict__ w_hh,   // [136,34]
    const float* __restrict__ b_ih,   // [136]
    const float* __restrict__ b_hh,   // [136]
    float* __restrict__ out)          // [B,T,34]
{
    __shared__ __align__(16) _Float16 a_lds[2][GB][KP]; // h/x operand, double-buffered

    const int tid  = threadIdx.x;
    const int lane = tid & 63;
    const int wv   = tid >> 6;      // wave id
    const int b    = lane & 15;     // batch (D col); tile-row rho when building W
    const int kg   = lane >> 4;     // k-group; D-row group

    // cell partition across waves: {9,9,8,8}
    const int nc   = (wv < 2) ? 9 : 8;
    const int base = (wv < 2) ? 9 * wv : 18 + 8 * (wv - 2);

    // ---- one-time: weight A-fragments (3 N-tiles x 2 K-chunks), prescaled fp16 ----
    f16x8 Wt[3][2];
    #pragma unroll
    for (int tau = 0; tau < 3; ++tau) {
        const int rhat = 16 * tau + b;
        const int jl = rhat >> 2, g = rhat & 3;
        const int r = (jl < nc) ? g * Hn + (base + jl) : -1;
        const float s = (g == 2) ? (2.f * L2E) : (-L2E);
        float swc[3] = {0.f, 0.f, 0.f};
        float bia = 0.f;
        if (r >= 0) {
            float ab = 0.f;
            for (int m = 0; m < Hn; ++m) {
                const float wi = w_ih[r * Hn + m];
                swc[0] += wi * fc0_w[m * 3 + 0];
                swc[1] += wi * fc0_w[m * 3 + 1];
                swc[2] += wi * fc0_w[m * 3 + 2];
                ab     += wi * fc0_b[m];
            }
            swc[0] *= s; swc[1] *= s; swc[2] *= s;
            bia = s * (ab + b_ih[r] + b_hh[r]);
        }
        #pragma unroll
        for (int ks = 0; ks < 2; ++ks) {
            f16x8 f;
            #pragma unroll
            for (int e = 0; e < 8; ++e) {
                const int k = ks * 32 + kg * 8 + e;
                float val = 0.f;
                if (r >= 0) {
                    if (k < 34)       val = s * w_hh[r * Hn + k];
                    else if (k < 37)  val = swc[k - 34];
                    else if (k < 40)  val = swc[k - 37];
                    else if (k == 40) val = bia;                          // bias_h
                    else if (k == 41) val = bia - (float)(_Float16)bia;   // bias_l
                }
                f[e] = (_Float16)val;
            }
            Wt[tau][ks] = f;
        }
    }

    // lane-local cells: jl = 4*tau + kg (tau=0,1 always valid; tau=2 iff 8+kg < nc)
    const bool has2 = (8 + kg < nc);
    float c0 = 0.f, c1 = 0.f, c2 = 0.f;
    float h0 = 0.f, h1 = 0.f, h2 = 0.f;

    // x staging: wave w stages batches 4w..4w+3 (12 lanes x 1 feature)
    const bool xact = (lane < 12);
    const int bx = 4 * wv + lane / 3;
    const int ix = lane - 3 * (lane / 3);

    // ---- zero both A buffers; barrier; bias-1.0 slots + x(0); barrier ----
    for (int i = tid; i < 2 * GB * KP; i += 256) ((_Float16*)a_lds)[i] = (_Float16)0.f;
    block_sync_lds();

    const long long bg = (long long)blockIdx.x * GB;
    const float* xblk = x + bg * (long long)(Tn * 3);
    float* oblk = out + bg * (long long)(Tn * Hn);
    const long long TH = (long long)Tn * Hn;

    if (tid < 32) {   // constant-1.0 slots (bias path), both buffers
        a_lds[tid >> 4][tid & 15][40] = (_Float16)1.f;
        a_lds[tid >> 4][tid & 15][41] = (_Float16)1.f;
    }
    if (xact) {
        const float xr = xblk[bx * (Tn * 3) + ix];
        const _Float16 xh = (_Float16)xr;
        a_lds[0][bx][34 + ix] = xh;
        a_lds[0][bx][37 + ix] = (_Float16)(xr - (float)xh);
    }
    block_sync_lds();

    // prime the x pipeline: xr_hold = x(1)
    float xr_hold = 0.f;
    if (xact && 1 < Tn)
        xr_hold = xblk[bx * (Tn * 3) + 3 + ix];

    // pointer-hoisted output cursor (stores h(t-1) at top of step t)
    float* pr = oblk + (long long)b * TH + base;

    for (int t = 0; t < Tn; ++t) {
        const int cur = t & 1, nxt = cur ^ 1;

        // ---- (1) data B-fragments first ----
        f16x8 av[2];
        #pragma unroll
        for (int ks = 0; ks < 2; ++ks)
            av[ks] = *(const f16x8*)(&a_lds[cur][b][ks * 32 + kg * 8]);

        // ---- (2) stage x(t+1) from xr_hold (load >= 1 step old: free wait) ----
        if (xact) {
            const _Float16 xh = (_Float16)xr_hold;
            a_lds[nxt][bx][34 + ix] = xh;
            a_lds[nxt][bx][37 + ix] = (_Float16)(xr_hold - (float)xh);
        }

        // ---- (3) h(t-1) stores (fire-and-forget) ----
        if (t) {
            pr[kg]     = h0;
            pr[4 + kg] = h1;
            if (has2) pr[8 + kg] = h2;
            pr += Hn;
        }

        // ---- (4) issue x(t+2) load ----
        float xr_next = 0.f;
        if (xact && t + 2 < Tn)
            xr_next = xblk[bx * (Tn * 3) + (t + 2) * 3 + ix];

        // ---- MFMA (swapped): acc[tau] regs = gates i,f,g,o of cell 4*tau+kg ----
        f32x4 acc[3];
        #pragma unroll
        for (int tau = 0; tau < 3; ++tau) {
            acc[tau] = f32x4{0.f, 0.f, 0.f, 0.f};
            #pragma unroll
            for (int ks = 0; ks < 2; ++ks)
                acc[tau] = __builtin_amdgcn_mfma_f32_16x16x32_f16(Wt[tau][ks], av[ks], acc[tau], 0, 0, 0);
        }

        // ---- lane-local fused-rcp nonlinearity + cell update ----
        {
            const float Ei = fexp2(acc[0][0]);
            const float Ef = fexp2(acc[0][1]);
            const float Eg = fexp2(acc[0][2]);
            const float Eo = fexp2(acc[0][3]);
            const float ig = (Eg - 1.f) * frcp((1.f + Ei) * (1.f + Eg));
            c0 = fmaf(frcp(1.f + Ef), c0, ig);
            const float ax = fminf(fmaxf(c0 * (2.f * L2E), -80.f), 80.f);
            const float Ec = fexp2(ax);
            h0 = (Ec - 1.f) * frcp((1.f + Eo) * (1.f + Ec));
            a_lds[nxt][b][base + kg] = (_Float16)h0;
        }
        {
            const float Ei = fexp2(acc[1][0]);
            const float Ef = fexp2(acc[1][1]);
            const float Eg = fexp2(acc[1][2]);
            const float Eo = fexp2(acc[1][3]);
            const float ig = (Eg - 1.f) * frcp((1.f + Ei) * (1.f + Eg));
            c1 = fmaf(frcp(1.f + Ef), c1, ig);
            const float ax = fminf(fmaxf(c1 * (2.f * L2E), -80.f), 80.f);
            const float Ec = fexp2(ax);
            h1 = (Ec - 1.f) * frcp((1.f + Eo) * (1.f + Ec));
            a_lds[nxt][b][base + 4 + kg] = (_Float16)h1;
        }
        if (has2) {
            const float Ei = fexp2(acc[2][0]);
            const float Ef = fexp2(acc[2][1]);
            const float Eg = fexp2(acc[2][2]);
            const float Eo = fexp2(acc[2][3]);
            const float ig = (Eg - 1.f) * frcp((1.f + Ei) * (1.f + Eg));
            c2 = fmaf(frcp(1.f + Ef), c2, ig);
            const float ax = fminf(fmaxf(c2 * (2.f * L2E), -80.f), 80.f);
            const float Ec = fexp2(ax);
            h2 = (Ec - 1.f) * frcp((1.f + Eo) * (1.f + Ec));
            a_lds[nxt][b][base + 8 + kg] = (_Float16)h2;
        }

        xr_hold = xr_next;   // advance the x pipeline

        block_sync_lds();    // the ONE sync/step: h(t) visible to all waves
    }

    // final store: h(Tn-1)
    {
        pr[kg]     = h0;
        pr[4 + kg] = h1;
        if (has2) pr[8 + kg] = h2;
    }
}

} // namespace

extern "C" void kernel_launch(void* const* d_in, const int* in_sizes, int n_in,
                              void* d_out, int out_size, void* d_ws, size_t ws_size,
                              hipStream_t stream) {
    const float* x     = (const float*)d_in[0];
    const float* fc0_w = (const float*)d_in[1];
    const float* fc0_b = (const float*)d_in[2];
    const float* w_ih  = (const float*)d_in[3];
    const float* w_hh  = (const float*)d_in[4];
    const float* b_ih  = (const float*)d_in[5];
    const float* b_hh  = (const float*)d_in[6];
    float* out = (float*)d_out;

    lstm_kernel<<<Bn / GB, 256, 0, stream>>>(x, fc0_w, fc0_b, w_ih, w_hh, b_ih, b_hh, out);
}